// Round 1
// baseline (496.513 us; speedup 1.0000x reference)
//
#include <hip/hip_runtime.h>
#include <math.h>

#define N_NODES 10000
#define N_EDGES 320000

__device__ __forceinline__ float ssp(float x) {
    // softplus(x) - ln(2), numerically stable
    float ax = fabsf(x);
    return fmaxf(x, 0.0f) + log1pf(expf(-ax)) - 0.69314718055994531f;
}

// ---------------- CSR build ----------------

__global__ void count_kernel(const int* __restrict__ dst, int* __restrict__ counts, int E) {
    int e = blockIdx.x * blockDim.x + threadIdx.x;
    if (e < E) atomicAdd(&counts[dst[e]], 1);
}

__global__ __launch_bounds__(1024) void scan_kernel(const int* __restrict__ counts,
                                                    int* __restrict__ offsets,
                                                    int* __restrict__ cursor, int n) {
    __shared__ int sums[1024];
    int t = threadIdx.x;
    const int CH = (n + 1023) / 1024;
    int base = t * CH;
    int local = 0;
    for (int i = 0; i < CH; ++i) {
        int idx = base + i;
        if (idx < n) local += counts[idx];
    }
    sums[t] = local;
    __syncthreads();
    for (int off = 1; off < 1024; off <<= 1) {
        int v = sums[t];
        int add = (t >= off) ? sums[t - off] : 0;
        __syncthreads();
        sums[t] = v + add;
        __syncthreads();
    }
    int run = (t == 0) ? 0 : sums[t - 1];  // exclusive prefix
    for (int i = 0; i < CH; ++i) {
        int idx = base + i;
        if (idx < n) {
            offsets[idx] = run;
            cursor[idx]  = run;
            run += counts[idx];
        }
    }
    if (t == 0) offsets[n] = sums[1023];
}

__global__ void scatter_kernel(const int* __restrict__ dst, int* __restrict__ cursor,
                               int* __restrict__ csr, int E) {
    int e = blockIdx.x * blockDim.x + threadIdx.x;
    if (e < E) {
        int d = dst[e];
        int p = atomicAdd(&cursor[d], 1);
        csr[p] = e;
    }
}

// ---------------- node pre-transform: x0 = f0@W1_0/8, x1T[(n,3,64)] = (f1.c @ W1_1)/8 ----------------

__global__ __launch_bounds__(256) void node_pre_kernel(
        const float* __restrict__ nf0, const float* __restrict__ nf1,
        const float* __restrict__ W1_0, const float* __restrict__ W1_1,
        float* __restrict__ x0, float* __restrict__ x1T) {
    const int n = blockIdx.x;
    const int t = threadIdx.x;
    __shared__ float s_f0[64];
    __shared__ float s_f1[192];
    if (t < 64) s_f0[t] = nf0[n*64 + t];
    else        s_f1[t-64] = nf1[n*192 + (t-64)];
    __syncthreads();
    if (t < 64) {
        float acc = 0.f;
        #pragma unroll 8
        for (int u = 0; u < 64; ++u) acc += s_f0[u] * W1_0[u*64 + t];
        x0[n*64 + t] = acc * 0.125f;
    } else {
        const int c = (t - 64) >> 6;
        const int w = t & 63;
        float acc = 0.f;
        #pragma unroll 8
        for (int u = 0; u < 64; ++u) acc += s_f1[u*3 + c] * W1_1[u*64 + w];
        x1T[n*192 + c*64 + w] = acc * 0.125f;
    }
}

// ---------------- main: gather edges (CSR), aggregate in registers, output transform ----------------

__global__ __launch_bounds__(256) void node_main_kernel(
    const float* __restrict__ nf0, const float* __restrict__ nf1,
    const float* __restrict__ nattr,
    const float* __restrict__ eemb, const float* __restrict__ eattr,
    const int* __restrict__ esrc,
    const int* __restrict__ offsets, const int* __restrict__ csr,
    const float* __restrict__ x0g, const float* __restrict__ x1g,
    const float* __restrict__ Wr1, const float* __restrict__ Wr2,
    const float* __restrict__ W2_0, const float* __restrict__ W2_1,
    const float* __restrict__ Wsc0, const float* __restrict__ Wsc1,
    float* __restrict__ out)
{
    const int n = blockIdx.x;
    const int t = threadIdx.x;
    const int u = t & 63;
    const int g = t >> 6;

    __shared__ float s_f0[64], s_f1[192], s_attr[4];
    __shared__ float s_h[8], s_y[4];
    __shared__ float s_xs0[64], s_xs1[192];      // xs1 in (c,u) layout
    __shared__ float s_agg0[128], s_agg1[384];   // agg1: [c][i], i<64=m01 row u, i>=64=m10 row u
    __shared__ float s_fa[256];
    __shared__ float s_n0[128];
    __shared__ float s_out[256];

    if (t < 64) s_f0[t] = nf0[n*64 + t];
    else        s_f1[t-64] = nf1[n*192 + (t-64)];
    if (t >= 192 && t < 196) s_attr[t-192] = nattr[n*4 + (t-192)];

    float a0 = 0.f, a1 = 0.f;
    const int start = offsets[n];
    const int end   = offsets[n+1];
    const float rs8 = 0.35355339059327373f;   // 1/sqrt(8)
    const float rs3 = 0.57735026918962576f;   // 1/sqrt(3)

    for (int idx = start; idx < end; ++idx) {
        const int e = csr[idx];
        const int src = esrc[e];
        // stage gathered source features
        if (t < 64) s_xs0[t] = x0g[src*64 + t];
        else        s_xs1[t-64] = x1g[src*192 + (t-64)];
        if (t >= 128 && t < 132) s_y[t-128] = eattr[e*4 + (t-128)];
        // h = ssp(emb @ Wr1 / sqrt8), threads 0..7
        if (t < 8) {
            float pre = 0.f;
            #pragma unroll
            for (int i = 0; i < 8; ++i) pre += eemb[e*8 + i] * Wr1[i*8 + t];
            s_h[t] = ssp(pre * rs8);
        }
        __syncthreads();
        // per-thread w columns: g==0 -> w0[u], w3[u]; g>=1 -> w1[u], w2[u]
        const int colA = (g == 0) ? u : (64 + u);
        const int colB = (g == 0) ? (192 + u) : (128 + u);
        float wa = 0.f, wb = 0.f;
        #pragma unroll
        for (int j = 0; j < 8; ++j) {
            const float hj = s_h[j];
            wa += hj * Wr2[j*256 + colA];
            wb += hj * Wr2[j*256 + colB];
        }
        wa *= rs8; wb *= rs8;
        const float y0 = s_y[0];
        if (g == 0) {
            a0 += wa * s_xs0[u] * y0;                                   // m00[u]
            const float d3 = s_xs1[u]*s_y[1] + s_xs1[64+u]*s_y[2] + s_xs1[128+u]*s_y[3];
            a1 += wb * d3 * rs3;                                        // m11[u]
        } else {
            const int c = g - 1;
            a0 += wa * s_xs0[u] * s_y[1+c];                             // m01[u][c]
            a1 += wb * s_xs1[c*64+u] * y0;                              // m10[u][c]
        }
        __syncthreads();
    }

    const float rs32 = 0.17677669529663687f;  // 1/sqrt(32)
    if (g == 0) {
        s_agg0[u]      = a0 * rs32;
        s_agg0[64+u]   = a1 * rs32;
    } else {
        const int c = g - 1;
        s_agg1[c*128 + u]      = a0 * rs32;
        s_agg1[c*128 + 64 + u] = a1 * rs32;
    }
    __syncthreads();
    s_fa[t] = s_f0[t >> 2] * s_attr[t & 3];
    __syncthreads();

    const float rs128 = 0.088388347648318447f;  // 1/sqrt(128)
    if (t < 128) {
        float acc = 0.f;
        #pragma unroll 4
        for (int i = 0; i < 128; ++i) acc += s_agg0[i] * W2_0[i*128 + t];
        acc *= rs128;
        float sc = 0.f;
        #pragma unroll 4
        for (int uv = 0; uv < 256; ++uv) sc += s_fa[uv] * Wsc0[uv*128 + t];
        acc += sc * 0.0625f;
        s_n0[t] = ssp(acc);  // scalars (t<64) and gates (t>=64)
    }
    __syncthreads();
    if (t < 64) s_out[t] = s_f0[t] + s_n0[t];
    if (t < 192) {
        const int w = t & 63;
        const int c = t >> 6;
        float acc = 0.f;
        #pragma unroll 4
        for (int i = 0; i < 128; ++i) acc += s_agg1[c*128 + i] * W2_1[i*64 + w];
        acc *= rs128;
        float sc = 0.f;
        #pragma unroll 4
        for (int uu = 0; uu < 64; ++uu) {
            const float* wp = Wsc1 + uu*256 + w;  // (uu*4+v)*64 + w
            float wv = s_attr[0]*wp[0] + s_attr[1]*wp[64] + s_attr[2]*wp[128] + s_attr[3]*wp[192];
            sc += s_f1[uu*3 + c] * wv;
        }
        acc += sc * 0.0625f;
        const float gated = acc * s_n0[64 + w];
        s_out[64 + w*3 + c] = s_f1[w*3 + c] + gated;
    }
    __syncthreads();
    out[n*256 + t] = s_out[t];
}

// ---------------- launch ----------------

extern "C" void kernel_launch(void* const* d_in, const int* in_sizes, int n_in,
                              void* d_out, int out_size, void* d_ws, size_t ws_size,
                              hipStream_t stream) {
    const float* nf0   = (const float*)d_in[0];
    const float* nf1   = (const float*)d_in[1];
    const float* nattr = (const float*)d_in[2];
    const float* eemb  = (const float*)d_in[3];
    const float* eattr = (const float*)d_in[4];
    const int*   esrc  = (const int*)d_in[5];
    const int*   edst  = (const int*)d_in[6];
    const float* W1_0  = (const float*)d_in[7];
    const float* W1_1  = (const float*)d_in[8];
    const float* Wr1   = (const float*)d_in[9];
    const float* Wr2   = (const float*)d_in[10];
    const float* W2_0  = (const float*)d_in[11];
    const float* W2_1  = (const float*)d_in[12];
    const float* Wsc0  = (const float*)d_in[13];
    const float* Wsc1  = (const float*)d_in[14];
    float* out = (float*)d_out;

    char* ws = (char*)d_ws;
    float* x0  = (float*)ws;   ws += (size_t)N_NODES*64*sizeof(float);
    float* x1T = (float*)ws;   ws += (size_t)N_NODES*192*sizeof(float);
    int* counts  = (int*)ws;   ws += (size_t)N_NODES*sizeof(int);
    int* offsets = (int*)ws;   ws += (size_t)(N_NODES+1)*sizeof(int);
    int* cursor  = (int*)ws;   ws += (size_t)N_NODES*sizeof(int);
    int* csr     = (int*)ws;   ws += (size_t)N_EDGES*sizeof(int);

    hipMemsetAsync(counts, 0, N_NODES*sizeof(int), stream);
    node_pre_kernel<<<N_NODES, 256, 0, stream>>>(nf0, nf1, W1_0, W1_1, x0, x1T);
    count_kernel<<<(N_EDGES+255)/256, 256, 0, stream>>>(edst, counts, N_EDGES);
    scan_kernel<<<1, 1024, 0, stream>>>(counts, offsets, cursor, N_NODES);
    scatter_kernel<<<(N_EDGES+255)/256, 256, 0, stream>>>(edst, cursor, csr, N_EDGES);
    node_main_kernel<<<N_NODES, 256, 0, stream>>>(nf0, nf1, nattr, eemb, eattr, esrc,
        offsets, csr, x0, x1T, Wr1, Wr2, W2_0, W2_1, Wsc0, Wsc1, out);
}